// Round 13
// baseline (528.884 us; speedup 1.0000x reference)
//
#include <hip/hip_runtime.h>
#include <hip/hip_bf16.h>

// SDE Euler-Maruyama: x_{k+1} = x_k + dt*(x_k @ A^T) + (sigma*sqrt(dt))*dW_k
// out[0] = x0, out[k+1] = x_{k+1}, out shape [1001, 1024, 256].
//
// R4 632 (split-role TLP) / R8 601 (replica-fused) / R11 440 (2-step fusion) /
// R12 408 (4-step fusion, butterfly transpose).
// R13: 8-STEP FUSION, transpose-free layout. Tile rows R = p*8 + j, 2 paths
// per block, quantities j in {x, nu0..nu6} (all 16 rows useful). C/D group g
// (lanes 16g..16g+15) regs r = tile rows 4g+r = EXACTLY the 4 prefix terms
// t those lanes need (t_j = M*row_j, M = dt*A): groups 0/2 (paths 0/1) hold
// t0..t3 -> compute y1..y4; groups 1/3 hold t4..t7 -> y5..y8 after a single
// shfl_xor(16) handoff of (cum4, y4). y_{b+k} = base + k*Pb + z_k where
// z_k = local prefix of (t, nu). O(M^2) dropped (~4e-5 accumulated).
// 512 blocks x 512 thr = 2 blocks/CU: independent barriers -> phase overlap
// at no extra MFMA (fixes R7's cost). 125 barriers total. dW loaded once
// (f32 window + bf16 stage); x stays f32 via shfl handoff.

typedef __attribute__((ext_vector_type(4))) float fvec4;
typedef __attribute__((ext_vector_type(8))) short svec8;
typedef __attribute__((ext_vector_type(4))) float f32x4;

constexpr int D = 256;
constexpr int BATCH = 1024;
constexpr int BD = BATCH * D;
constexpr int NSTEPS = 1000;
constexpr float DT = 0.001f;
constexpr float SQRT_DT = 0.03162277660168379f;  // sqrt(0.001)

__device__ __forceinline__ unsigned short f2bf(float f) {
  unsigned int u = __float_as_uint(f);
  u += 0x7FFFu + ((u >> 16) & 1u);
  return (unsigned short)(u >> 16);
}

// LDS-only barrier: no vmcnt drain (global loads/stores stay in flight).
__device__ __forceinline__ void lds_barrier() {
  __builtin_amdgcn_sched_barrier(0);
  asm volatile("s_waitcnt lgkmcnt(0)" ::: "memory");
  __builtin_amdgcn_s_barrier();
  __builtin_amdgcn_sched_barrier(0);
}

// xb u16 index for (row R, col c), XOR-swizzled
#define XIDX(R, c) ((((R) << 8)) + ((c) ^ (((R)&7) << 5)))

__global__ __launch_bounds__(512, 4)
void sde_em_kernel(const float* __restrict__ x0, const float* __restrict__ Amat,
                   const float* __restrict__ sigma, const float* __restrict__ dW,
                   float* __restrict__ out) {
  // 16 rows x 256 cols bf16, double-buffered (16 KB)
  __shared__ __align__(16) unsigned short xb[2][16 * 256];

  const int t = threadIdx.x;
  const int w = t >> 6;          // wave 0..7: owns cols w*32 .. w*32+31
  const int l = t & 63;
  const int l16 = l & 15;
  const int q = l >> 4;          // lane group 0..3
  const int p = l >> 5;          // path within block (0 or 1)
  const int hi = q & 1;          // 0: steps 1-4, 1: steps 5-8

  // ---- one-time: B = DT*A^T fragments, bf16, registers ----
  svec8 bfr[2][8];
#pragma unroll
  for (int tt = 0; tt < 2; ++tt) {
#pragma unroll
    for (int kt = 0; kt < 8; ++kt) {
      const float* src =
          Amat + (size_t)((w << 5) + (tt << 4) + l16) * D + (kt << 5) + (q << 3);
      fvec4 a0 = *(const fvec4*)(src);
      fvec4 a1 = *(const fvec4*)(src + 4);
      svec8 b;
      b[0] = (short)f2bf(DT * a0[0]); b[1] = (short)f2bf(DT * a0[1]);
      b[2] = (short)f2bf(DT * a0[2]); b[3] = (short)f2bf(DT * a0[3]);
      b[4] = (short)f2bf(DT * a1[0]); b[5] = (short)f2bf(DT * a1[1]);
      b[6] = (short)f2bf(DT * a1[2]); b[7] = (short)f2bf(DT * a1[3]);
      bfr[tt][kt] = b;
    }
  }

  // ---- per-lane role: (path p, cols c0 and c0+16, steps hi*4+1..hi*4+4) ----
  const int c0 = (w << 5) + l16;
  const size_t go = (size_t)((blockIdx.x << 1) + p) * D + c0;
  const float sg0 = sigma[c0] * SQRT_DT;
  const float sg1 = sigma[c0 + 16] * SQRT_DT;
  float xs0 = x0[go];
  float xs1 = x0[go + 16];

  // f32 noise window: this lane's 4 steps (hi*4 .. hi*4+3)
  float nv0[4], nv1[4];
#pragma unroll
  for (int k = 0; k < 4; ++k) {
    const float* dp = dW + (size_t)((hi << 2) + k) * BD + go;
    nv0[k] = __builtin_nontemporal_load(dp);
    nv1[k] = __builtin_nontemporal_load(dp + 16);
  }

  const int pr = p << 3;
  // seed xb[0]: low lanes stage rows pr+1..pr+4 (nu0..nu3); high lanes stage
  // rows pr+5..pr+7 (nu4..nu6) and row pr (x).
#pragma unroll
  for (int k = 0; k < 4; ++k) {
    const int R = hi ? ((k == 3) ? pr : pr + 5 + k) : pr + 1 + k;
    const float v0 = (hi && k == 3) ? xs0 : sg0 * nv0[k];
    const float v1 = (hi && k == 3) ? xs1 : sg1 * nv1[k];
    xb[0][XIDX(R, c0)] = f2bf(v0);
    xb[0][XIDX(R, c0 + 16)] = f2bf(v1);
  }
  // out[0] = x0 (block slice = 2*D = 512 floats = 1/thread, coalesced)
  {
    const size_t g2 = (size_t)(blockIdx.x << 1) * D + t;
    out[g2] = x0[g2];
  }
  __syncthreads();

  for (int it = 0; it < 125; ++it) {
    const int n = it << 3;
    const int rb = it & 1, wb = rb ^ 1;

    // prefetch next window: dW[n+8+hi*4 .. +3] (consumed next iter)
    float pf0[4], pf1[4];
#pragma unroll
    for (int j = 0; j < 4; ++j) {
      int st = n + 8 + (hi << 2) + j;
      st = (st < NSTEPS) ? st : (NSTEPS - 1);
      const float* dp = dW + (size_t)st * BD + go;
      pf0[j] = __builtin_nontemporal_load(dp);
      pf1[j] = __builtin_nontemporal_load(dp + 16);
    }

    // MFMA: acc regs = t_{4*q_local + r} for this lane's (path, half)
    f32x4 acc0 = (f32x4){0.f, 0.f, 0.f, 0.f};
    f32x4 acc1 = (f32x4){0.f, 0.f, 0.f, 0.f};
#pragma unroll
    for (int kt = 0; kt < 8; ++kt) {
      svec8 a = *(const svec8*)
          &xb[rb][(l16 << 8) + (((kt << 5) + (q << 3)) ^ ((l16 & 7) << 5))];
      acc0 = __builtin_amdgcn_mfma_f32_16x16x32_bf16(a, bfr[0][kt], acc0, 0, 0, 0);
      acc1 = __builtin_amdgcn_mfma_f32_16x16x32_bf16(a, bfr[1][kt], acc1, 0, 0, 0);
    }

    // local prefix sums s_k and z_k (z_k = sum_{i<=k} s_i + sum_{i<k} nu_i)
    const float s1_0 = acc0[0], s2_0 = s1_0 + acc0[1];
    const float s3_0 = s2_0 + acc0[2], s4_0 = s3_0 + acc0[3];
    const float s1_1 = acc1[0], s2_1 = s1_1 + acc1[1];
    const float s3_1 = s2_1 + acc1[2], s4_1 = s3_1 + acc1[3];
    const float z1_0 = s1_0 + sg0 * nv0[0];
    const float z2_0 = z1_0 + s2_0 + sg0 * nv0[1];
    const float z3_0 = z2_0 + s3_0 + sg0 * nv0[2];
    const float z4_0 = z3_0 + s4_0 + sg0 * nv0[3];
    const float z1_1 = s1_1 + sg1 * nv1[0];
    const float z2_1 = z1_1 + s2_1 + sg1 * nv1[1];
    const float z3_1 = z2_1 + s3_1 + sg1 * nv1[2];
    const float z4_1 = z3_1 + s4_1 + sg1 * nv1[3];

    // handoff low->high: (cum4 = s4, y4 = x + z4)
    const float rA0 = __shfl_xor(s4_0, 16);
    const float rB0 = __shfl_xor(xs0 + z4_0, 16);
    const float rA1 = __shfl_xor(s4_1, 16);
    const float rB1 = __shfl_xor(xs1 + z4_1, 16);
    const float Pb0 = hi ? rA0 : 0.f, base0 = hi ? rB0 : xs0;
    const float Pb1 = hi ? rA1 : 0.f, base1 = hi ? rB1 : xs1;

    // y_{base+k} = base + k*Pb + z_k
    const float b1_0 = base0 + Pb0, b2_0 = b1_0 + Pb0;
    const float b3_0 = b2_0 + Pb0, b4_0 = b3_0 + Pb0;
    const float b1_1 = base1 + Pb1, b2_1 = b1_1 + Pb1;
    const float b3_1 = b2_1 + Pb1, b4_1 = b3_1 + Pb1;
    const float y1_0 = b1_0 + z1_0, y2_0 = b2_0 + z2_0;
    const float y3_0 = b3_0 + z3_0, y4_0 = b4_0 + z4_0;
    const float y1_1 = b1_1 + z1_1, y2_1 = b2_1 + z2_1;
    const float y3_1 = b3_1 + z3_1, y4_1 = b4_1 + z4_1;

    // stores: steps n+1+hi*4 .. n+4+hi*4
    float* ob = out + (size_t)(n + 1 + (hi << 2)) * BD + go;
    __builtin_nontemporal_store(y1_0, ob);
    __builtin_nontemporal_store(y1_1, ob + 16);
    __builtin_nontemporal_store(y2_0, ob + BD);
    __builtin_nontemporal_store(y2_1, ob + BD + 16);
    __builtin_nontemporal_store(y3_0, ob + 2 * BD);
    __builtin_nontemporal_store(y3_1, ob + 2 * BD + 16);
    __builtin_nontemporal_store(y4_0, ob + 3 * BD);
    __builtin_nontemporal_store(y4_1, ob + 3 * BD + 16);

    // x handoff high->low: high's y4 is the global y8 = next x
    const float nx0 = __shfl_xor(y4_0, 16);
    const float nx1 = __shfl_xor(y4_1, 16);
    xs0 = hi ? xs0 : nx0;
    xs1 = hi ? xs1 : nx1;

    // stage next tile: low -> rows pr+1..4 (nu'_0..3 = pf); high -> rows
    // pr+5..7 (nu'_4..6 = pf[0..2]) and row pr (x' = y8)
#pragma unroll
    for (int k = 0; k < 4; ++k) {
      const int R = hi ? ((k == 3) ? pr : pr + 5 + k) : pr + 1 + k;
      const float v0 = (hi && k == 3) ? y4_0 : sg0 * pf0[k];
      const float v1 = (hi && k == 3) ? y4_1 : sg1 * pf1[k];
      xb[wb][XIDX(R, c0)] = f2bf(v0);
      xb[wb][XIDX(R, c0 + 16)] = f2bf(v1);
    }
#pragma unroll
    for (int k = 0; k < 4; ++k) { nv0[k] = pf0[k]; nv1[k] = pf1[k]; }

    lds_barrier();
  }
}

extern "C" void kernel_launch(void* const* d_in, const int* in_sizes, int n_in,
                              void* d_out, int out_size, void* d_ws, size_t ws_size,
                              hipStream_t stream) {
  const float* x0    = (const float*)d_in[0];
  const float* Amat  = (const float*)d_in[1];
  const float* sigma = (const float*)d_in[2];
  const float* dW    = (const float*)d_in[3];
  float* out = (float*)d_out;
  sde_em_kernel<<<dim3(512), dim3(512), 0, stream>>>(x0, Amat, sigma, dW, out);
}

// Round 14
// 424.723 us; speedup vs baseline: 1.2452x; 1.2452x over previous
//
#include <hip/hip_runtime.h>
#include <hip/hip_bf16.h>

// SDE Euler-Maruyama: x_{k+1} = x_k + dt*(x_k @ A^T) + (sigma*sqrt(dt))*dW_k
// out[0] = x0, out[k+1] = x_{k+1}, out shape [1001, 1024, 256].
//
// R4 632 / R8 601 / R11 440 (2-step fusion) / R12 408 (4-step fusion,
// butterfly transpose) / R13 528 (8-step + 2 blk/CU regressed: VGPR cap
// forced spills + double-handoff chain).
// R14 = R12 with PATH-MAJOR rows: R = 4*path + quantity, quantities
// {x, nu0, nu1, nu2}. C/D group g regs 0-3 = rows 4g..4g+3 = path g's
// {Mx, Mnu0, Mnu1, Mnu2} -- the exact prefix terms the lanes that update
// path g need, in register order. XPOSE/SELQ deleted: zero shuffles, zero
// cndmask on the serial chain. Otherwise identical to R12:
//   y1 = x + p1 + nu0, y_k = y_{k-1} + p_k + nu_{k-1}, p_k = t0+..+t_{k-1}
//   (M = dt*A, t0 = Mx, t_j = Mnu_{j-1}; O(M^2) dropped ~1e-4)

typedef __attribute__((ext_vector_type(2))) float fvec2;
typedef __attribute__((ext_vector_type(4))) float fvec4;
typedef __attribute__((ext_vector_type(8))) short svec8;
typedef __attribute__((ext_vector_type(4))) float f32x4;

constexpr int D = 256;
constexpr int BATCH = 1024;
constexpr int BD = BATCH * D;
constexpr int NSTEPS = 1000;
constexpr float DT = 0.001f;
constexpr float SQRT_DT = 0.03162277660168379f;  // sqrt(0.001)

__device__ __forceinline__ unsigned short f2bf(float f) {
  unsigned int u = __float_as_uint(f);
  u += 0x7FFFu + ((u >> 16) & 1u);
  return (unsigned short)(u >> 16);
}

// LDS-only barrier: no vmcnt drain (global loads/stores stay in flight).
__device__ __forceinline__ void lds_barrier() {
  __builtin_amdgcn_sched_barrier(0);
  asm volatile("s_waitcnt lgkmcnt(0)" ::: "memory");
  __builtin_amdgcn_s_barrier();
  __builtin_amdgcn_sched_barrier(0);
}

// xb u16 index for (row R, col c), XOR-swizzled
#define XIDX(R, c) ((((R) << 8)) + ((c) ^ (((R)&7) << 5)))

__global__ __launch_bounds__(512, 2)
void sde_em_kernel(const float* __restrict__ x0, const float* __restrict__ Amat,
                   const float* __restrict__ sigma, const float* __restrict__ dW,
                   float* __restrict__ out) {
  // xb: 16 rows (R = 4*path + j) x 256 cols bf16, double-buffered (16 KB)
  __shared__ __align__(16) unsigned short xb[2][16 * 256];

  const int t = threadIdx.x;
  const int w = t >> 6;          // wave 0..7: owns cols w*32 .. w*32+31
  const int l = t & 63;
  const int l16 = l & 15;
  const int q = l >> 4;          // lane group 0..3 = path q

  // ---- one-time: B = DT*A^T fragments, bf16, registers ----
  svec8 bfr[2][8];
#pragma unroll
  for (int tt = 0; tt < 2; ++tt) {
#pragma unroll
    for (int kt = 0; kt < 8; ++kt) {
      const float* src =
          Amat + (size_t)((w << 5) + (tt << 4) + l16) * D + (kt << 5) + (q << 3);
      fvec4 a0 = *(const fvec4*)(src);
      fvec4 a1 = *(const fvec4*)(src + 4);
      svec8 b;
      b[0] = (short)f2bf(DT * a0[0]); b[1] = (short)f2bf(DT * a0[1]);
      b[2] = (short)f2bf(DT * a0[2]); b[3] = (short)f2bf(DT * a0[3]);
      b[4] = (short)f2bf(DT * a1[0]); b[5] = (short)f2bf(DT * a1[1]);
      b[6] = (short)f2bf(DT * a1[2]); b[7] = (short)f2bf(DT * a1[3]);
      bfr[tt][kt] = b;
    }
  }

  // ---- update role: lane (group q, l16) owns path q, cols c0, c0+16 ----
  const int c0 = (w << 5) + l16;
  const size_t go = (size_t)((blockIdx.x << 2) + q) * D + c0;
  const float sg0 = sigma[c0] * SQRT_DT;
  const float sg1 = sigma[c0 + 16] * SQRT_DT;
  float xs0 = x0[go];
  float xs1 = x0[go + 16];

  // rolling dW window: dv[i] = dW[step n+i], i = 0..6
  float dv0[7], dv1[7];
#pragma unroll
  for (int i = 0; i < 7; ++i) {
    dv0[i] = __builtin_nontemporal_load(dW + (size_t)i * BD + go);
    dv1[i] = __builtin_nontemporal_load(dW + (size_t)i * BD + go + 16);
  }

  // seed xb[0]: rows 4q+0 (x), 4q+1..3 (nu from steps 0,1,2)
  const int pr = q << 2;
  xb[0][XIDX(pr, c0)] = f2bf(xs0);
  xb[0][XIDX(pr, c0 + 16)] = f2bf(xs1);
  xb[0][XIDX(pr + 1, c0)] = f2bf(sg0 * dv0[0]);
  xb[0][XIDX(pr + 1, c0 + 16)] = f2bf(sg1 * dv1[0]);
  xb[0][XIDX(pr + 2, c0)] = f2bf(sg0 * dv0[1]);
  xb[0][XIDX(pr + 2, c0 + 16)] = f2bf(sg1 * dv1[1]);
  xb[0][XIDX(pr + 3, c0)] = f2bf(sg0 * dv0[2]);
  xb[0][XIDX(pr + 3, c0 + 16)] = f2bf(sg1 * dv1[2]);

  // out[0] = x0 (vectorized copy, all 512 threads)
  {
    const int p2 = t >> 7;
    const int c2 = (t & 127) << 1;
    const size_t g2 = (size_t)((blockIdx.x << 2) + p2) * D + c2;
    fvec2 v = *(const fvec2*)(x0 + g2);
    __builtin_nontemporal_store(v, (fvec2*)(out + g2));
  }

  __syncthreads();

#define ITER(n_, RB, WB)                                                       \
  {                                                                            \
    /* prefetch dW[n+7 .. n+10] (fills window tail after roll) */              \
    float pf0[4], pf1[4];                                                      \
    _Pragma("unroll") for (int j = 0; j < 4; ++j) {                            \
      int i_ = (n_) + 7 + j;                                                   \
      i_ = (i_ < NSTEPS) ? i_ : (NSTEPS - 1);                                  \
      pf0[j] = __builtin_nontemporal_load(dW + (size_t)i_ * BD + go);          \
      pf1[j] = __builtin_nontemporal_load(dW + (size_t)i_ * BD + go + 16);     \
    }                                                                          \
    f32x4 acc0 = (f32x4){0.f, 0.f, 0.f, 0.f};                                  \
    f32x4 acc1 = (f32x4){0.f, 0.f, 0.f, 0.f};                                  \
    _Pragma("unroll") for (int kt = 0; kt < 8; ++kt) {                         \
      svec8 a = *(const svec8*)                                                \
          &xb[RB][(l16 << 8) + (((kt << 5) + (q << 3)) ^ ((l16 & 7) << 5))];   \
      acc0 = __builtin_amdgcn_mfma_f32_16x16x32_bf16(a, bfr[0][kt], acc0,      \
                                                     0, 0, 0);                 \
      acc1 = __builtin_amdgcn_mfma_f32_16x16x32_bf16(a, bfr[1][kt], acc1,      \
                                                     0, 0, 0);                 \
    }                                                                          \
    /* group q's regs ARE path q's prefix terms: no shuffles needed */         \
    const float p1A = acc0[0], p2A = p1A + acc0[1];                            \
    const float p3A = p2A + acc0[2], p4A = p3A + acc0[3];                      \
    const float p1B = acc1[0], p2B = p1B + acc1[1];                            \
    const float p3B = p2B + acc1[2], p4B = p3B + acc1[3];                      \
    float* ob_ = out + (size_t)((n_) + 1) * BD + go;                           \
    xs0 = __builtin_fmaf(sg0, dv0[0], xs0) + p1A;                              \
    xs1 = __builtin_fmaf(sg1, dv1[0], xs1) + p1B;                              \
    __builtin_nontemporal_store(xs0, ob_);                                     \
    __builtin_nontemporal_store(xs1, ob_ + 16);                                \
    xs0 = __builtin_fmaf(sg0, dv0[1], xs0) + p2A;                              \
    xs1 = __builtin_fmaf(sg1, dv1[1], xs1) + p2B;                              \
    __builtin_nontemporal_store(xs0, ob_ + BD);                                \
    __builtin_nontemporal_store(xs1, ob_ + BD + 16);                           \
    xs0 = __builtin_fmaf(sg0, dv0[2], xs0) + p3A;                              \
    xs1 = __builtin_fmaf(sg1, dv1[2], xs1) + p3B;                              \
    __builtin_nontemporal_store(xs0, ob_ + 2 * BD);                            \
    __builtin_nontemporal_store(xs1, ob_ + 2 * BD + 16);                       \
    xs0 = __builtin_fmaf(sg0, dv0[3], xs0) + p4A;                              \
    xs1 = __builtin_fmaf(sg1, dv1[3], xs1) + p4B;                              \
    __builtin_nontemporal_store(xs0, ob_ + 3 * BD);                            \
    __builtin_nontemporal_store(xs1, ob_ + 3 * BD + 16);                       \
    /* stage next tile: nu rows first (depend only on window), x row last */   \
    xb[WB][XIDX(pr + 1, c0)] = f2bf(sg0 * dv0[4]);                             \
    xb[WB][XIDX(pr + 1, c0 + 16)] = f2bf(sg1 * dv1[4]);                        \
    xb[WB][XIDX(pr + 2, c0)] = f2bf(sg0 * dv0[5]);                             \
    xb[WB][XIDX(pr + 2, c0 + 16)] = f2bf(sg1 * dv1[5]);                        \
    xb[WB][XIDX(pr + 3, c0)] = f2bf(sg0 * dv0[6]);                             \
    xb[WB][XIDX(pr + 3, c0 + 16)] = f2bf(sg1 * dv1[6]);                        \
    xb[WB][XIDX(pr, c0)] = f2bf(xs0);                                          \
    xb[WB][XIDX(pr, c0 + 16)] = f2bf(xs1);                                     \
    /* roll window by 4 */                                                     \
    dv0[0] = dv0[4]; dv0[1] = dv0[5]; dv0[2] = dv0[6];                         \
    dv0[3] = pf0[0]; dv0[4] = pf0[1]; dv0[5] = pf0[2]; dv0[6] = pf0[3];        \
    dv1[0] = dv1[4]; dv1[1] = dv1[5]; dv1[2] = dv1[6];                         \
    dv1[3] = pf1[0]; dv1[4] = pf1[1]; dv1[5] = pf1[2]; dv1[6] = pf1[3];        \
    lds_barrier();                                                             \
  }

  // 250 fused iterations (n = 0, 4, ..., 996), x2 unroll for buffer parity
  for (int k = 0; k < NSTEPS / 4; k += 2) {
    ITER(4 * k, 0, 1);
    ITER(4 * k + 4, 1, 0);
  }
#undef ITER
}

extern "C" void kernel_launch(void* const* d_in, const int* in_sizes, int n_in,
                              void* d_out, int out_size, void* d_ws, size_t ws_size,
                              hipStream_t stream) {
  const float* x0    = (const float*)d_in[0];
  const float* Amat  = (const float*)d_in[1];
  const float* sigma = (const float*)d_in[2];
  const float* dW    = (const float*)d_in[3];
  float* out = (float*)d_out;
  sde_em_kernel<<<dim3(256), dim3(512), 0, stream>>>(x0, Amat, sigma, dW, out);
}

// Round 15
// 419.506 us; speedup vs baseline: 1.2607x; 1.0124x over previous
//
#include <hip/hip_runtime.h>
#include <hip/hip_bf16.h>

// SDE Euler-Maruyama: x_{k+1} = x_k + dt*(x_k @ A^T) + (sigma*sqrt(dt))*dW_k
// out[0] = x0, out[k+1] = x_{k+1}, out shape [1001, 1024, 256].
//
// R4 632 / R8 601 / R11 440 / R12 408 (4-step fusion + butterfly) /
// R13 528 (8-step+2blk/CU regressed) / R14 424 (path-major, no shuffles).
// R15 = R14 + ADJACENT-COLUMN PAIRING: B-frag chain tt loads A-row
// w*32 + 2*l16 + tt, so lane l's acc chains cover adjacent out-cols
// 2*l16, 2*l16+1 -> fvec2 dW loads (4 vs 8), fvec2 out stores (4 vs 8),
// u32 xb staging (4 vs 8), half the address math. Numerics identical:
//   y_k = y_{k-1} + p_k + nu_{k-1}, p_k = t0+..+t_{k-1}
//   (M = dt*A, t0 = Mx, t_j = Mnu_{j-1}; O(M^2) dropped ~1e-4)

typedef __attribute__((ext_vector_type(2))) float fvec2;
typedef __attribute__((ext_vector_type(4))) float fvec4;
typedef __attribute__((ext_vector_type(8))) short svec8;
typedef __attribute__((ext_vector_type(4))) float f32x4;

constexpr int D = 256;
constexpr int BATCH = 1024;
constexpr int BD = BATCH * D;
constexpr int NSTEPS = 1000;
constexpr float DT = 0.001f;
constexpr float SQRT_DT = 0.03162277660168379f;  // sqrt(0.001)

__device__ __forceinline__ unsigned short f2bf(float f) {
  unsigned int u = __float_as_uint(f);
  u += 0x7FFFu + ((u >> 16) & 1u);
  return (unsigned short)(u >> 16);
}

__device__ __forceinline__ unsigned int pack2bf(float a, float b) {
  return (unsigned int)f2bf(a) | ((unsigned int)f2bf(b) << 16);
}

// LDS-only barrier: no vmcnt drain (global loads/stores stay in flight).
__device__ __forceinline__ void lds_barrier() {
  __builtin_amdgcn_sched_barrier(0);
  asm volatile("s_waitcnt lgkmcnt(0)" ::: "memory");
  __builtin_amdgcn_s_barrier();
  __builtin_amdgcn_sched_barrier(0);
}

// xb u16 index for (row R, col c), XOR-swizzled (XOR touches bits >=5 of the
// u16 index, so an even/odd column pair stays adjacent and u32-aligned)
#define XIDX(R, c) ((((R) << 8)) + ((c) ^ (((R)&7) << 5)))

__global__ __launch_bounds__(512, 2)
void sde_em_kernel(const float* __restrict__ x0, const float* __restrict__ Amat,
                   const float* __restrict__ sigma, const float* __restrict__ dW,
                   float* __restrict__ out) {
  // xb: 16 rows (R = 4*path + j) x 256 cols bf16, double-buffered (16 KB)
  __shared__ __align__(16) unsigned short xb[2][16 * 256];

  const int t = threadIdx.x;
  const int w = t >> 6;          // wave 0..7: owns cols w*32 .. w*32+31
  const int l = t & 63;
  const int l16 = l & 15;
  const int q = l >> 4;          // lane group 0..3 = path q

  // ---- one-time: B = DT*A^T fragments, bf16, registers ----
  // chain tt covers out-col n = w*32 + 2*l16 + tt  (adjacent pair per lane)
  svec8 bfr[2][8];
#pragma unroll
  for (int tt = 0; tt < 2; ++tt) {
#pragma unroll
    for (int kt = 0; kt < 8; ++kt) {
      const float* src =
          Amat + (size_t)((w << 5) + (l16 << 1) + tt) * D + (kt << 5) + (q << 3);
      fvec4 a0 = *(const fvec4*)(src);
      fvec4 a1 = *(const fvec4*)(src + 4);
      svec8 b;
      b[0] = (short)f2bf(DT * a0[0]); b[1] = (short)f2bf(DT * a0[1]);
      b[2] = (short)f2bf(DT * a0[2]); b[3] = (short)f2bf(DT * a0[3]);
      b[4] = (short)f2bf(DT * a1[0]); b[5] = (short)f2bf(DT * a1[1]);
      b[6] = (short)f2bf(DT * a1[2]); b[7] = (short)f2bf(DT * a1[3]);
      bfr[tt][kt] = b;
    }
  }

  // ---- update role: lane (group q, l16) owns path q, cols c0, c0+1 ----
  const int c0 = (w << 5) + (l16 << 1);
  const size_t go = (size_t)((blockIdx.x << 2) + q) * D + c0;
  const fvec2 sgv = *(const fvec2*)(sigma + c0);
  const float sg0 = sgv[0] * SQRT_DT;
  const float sg1 = sgv[1] * SQRT_DT;
  fvec2 xv = *(const fvec2*)(x0 + go);
  float xs0 = xv[0], xs1 = xv[1];

  // rolling dW window: dv[i] = dW[step n+i] (cols c0, c0+1), i = 0..6
  fvec2 dv[7];
#pragma unroll
  for (int i = 0; i < 7; ++i)
    dv[i] = __builtin_nontemporal_load((const fvec2*)(dW + (size_t)i * BD + go));

  // seed xb[0]: rows 4q+0 (x), 4q+1..3 (nu from steps 0,1,2)
  const int pr = q << 2;
  *(unsigned int*)&xb[0][XIDX(pr, c0)] = pack2bf(xs0, xs1);
  *(unsigned int*)&xb[0][XIDX(pr + 1, c0)] = pack2bf(sg0 * dv[0][0], sg1 * dv[0][1]);
  *(unsigned int*)&xb[0][XIDX(pr + 2, c0)] = pack2bf(sg0 * dv[1][0], sg1 * dv[1][1]);
  *(unsigned int*)&xb[0][XIDX(pr + 3, c0)] = pack2bf(sg0 * dv[2][0], sg1 * dv[2][1]);

  // out[0] = x0 (vectorized copy, all 512 threads)
  {
    const int p2 = t >> 7;
    const int c2 = (t & 127) << 1;
    const size_t g2 = (size_t)((blockIdx.x << 2) + p2) * D + c2;
    fvec2 v = *(const fvec2*)(x0 + g2);
    __builtin_nontemporal_store(v, (fvec2*)(out + g2));
  }

  __syncthreads();

#define ITER(n_, RB, WB)                                                       \
  {                                                                            \
    /* prefetch dW[n+7 .. n+10] (fills window tail after roll) */              \
    fvec2 pf[4];                                                               \
    _Pragma("unroll") for (int j = 0; j < 4; ++j) {                            \
      int i_ = (n_) + 7 + j;                                                   \
      i_ = (i_ < NSTEPS) ? i_ : (NSTEPS - 1);                                  \
      pf[j] = __builtin_nontemporal_load(                                      \
          (const fvec2*)(dW + (size_t)i_ * BD + go));                          \
    }                                                                          \
    f32x4 acc0 = (f32x4){0.f, 0.f, 0.f, 0.f};                                  \
    f32x4 acc1 = (f32x4){0.f, 0.f, 0.f, 0.f};                                  \
    _Pragma("unroll") for (int kt = 0; kt < 8; ++kt) {                         \
      svec8 a = *(const svec8*)                                                \
          &xb[RB][(l16 << 8) + (((kt << 5) + (q << 3)) ^ ((l16 & 7) << 5))];   \
      acc0 = __builtin_amdgcn_mfma_f32_16x16x32_bf16(a, bfr[0][kt], acc0,      \
                                                     0, 0, 0);                 \
      acc1 = __builtin_amdgcn_mfma_f32_16x16x32_bf16(a, bfr[1][kt], acc1,      \
                                                     0, 0, 0);                 \
    }                                                                          \
    /* group q's regs ARE path q's prefix terms (cols c0, c0+1) */             \
    const float p1A = acc0[0], p2A = p1A + acc0[1];                            \
    const float p3A = p2A + acc0[2], p4A = p3A + acc0[3];                      \
    const float p1B = acc1[0], p2B = p1B + acc1[1];                            \
    const float p3B = p2B + acc1[2], p4B = p3B + acc1[3];                      \
    float* ob_ = out + (size_t)((n_) + 1) * BD + go;                           \
    xs0 = __builtin_fmaf(sg0, dv[0][0], xs0) + p1A;                            \
    xs1 = __builtin_fmaf(sg1, dv[0][1], xs1) + p1B;                            \
    __builtin_nontemporal_store((fvec2){xs0, xs1}, (fvec2*)ob_);               \
    xs0 = __builtin_fmaf(sg0, dv[1][0], xs0) + p2A;                            \
    xs1 = __builtin_fmaf(sg1, dv[1][1], xs1) + p2B;                            \
    __builtin_nontemporal_store((fvec2){xs0, xs1}, (fvec2*)(ob_ + BD));        \
    xs0 = __builtin_fmaf(sg0, dv[2][0], xs0) + p3A;                            \
    xs1 = __builtin_fmaf(sg1, dv[2][1], xs1) + p3B;                            \
    __builtin_nontemporal_store((fvec2){xs0, xs1}, (fvec2*)(ob_ + 2 * BD));    \
    xs0 = __builtin_fmaf(sg0, dv[3][0], xs0) + p4A;                            \
    xs1 = __builtin_fmaf(sg1, dv[3][1], xs1) + p4B;                            \
    __builtin_nontemporal_store((fvec2){xs0, xs1}, (fvec2*)(ob_ + 3 * BD));    \
    /* stage next tile: nu rows first, x row last */                           \
    *(unsigned int*)&xb[WB][XIDX(pr + 1, c0)] =                                \
        pack2bf(sg0 * dv[4][0], sg1 * dv[4][1]);                               \
    *(unsigned int*)&xb[WB][XIDX(pr + 2, c0)] =                                \
        pack2bf(sg0 * dv[5][0], sg1 * dv[5][1]);                               \
    *(unsigned int*)&xb[WB][XIDX(pr + 3, c0)] =                                \
        pack2bf(sg0 * dv[6][0], sg1 * dv[6][1]);                               \
    *(unsigned int*)&xb[WB][XIDX(pr, c0)] = pack2bf(xs0, xs1);                 \
    /* roll window by 4 */                                                     \
    dv[0] = dv[4]; dv[1] = dv[5]; dv[2] = dv[6];                               \
    dv[3] = pf[0]; dv[4] = pf[1]; dv[5] = pf[2]; dv[6] = pf[3];                \
    lds_barrier();                                                             \
  }

  // 250 fused iterations (n = 0, 4, ..., 996), x2 unroll for buffer parity
  for (int k = 0; k < NSTEPS / 4; k += 2) {
    ITER(4 * k, 0, 1);
    ITER(4 * k + 4, 1, 0);
  }
#undef ITER
}

extern "C" void kernel_launch(void* const* d_in, const int* in_sizes, int n_in,
                              void* d_out, int out_size, void* d_ws, size_t ws_size,
                              hipStream_t stream) {
  const float* x0    = (const float*)d_in[0];
  const float* Amat  = (const float*)d_in[1];
  const float* sigma = (const float*)d_in[2];
  const float* dW    = (const float*)d_in[3];
  float* out = (float*)d_out;
  sde_em_kernel<<<dim3(256), dim3(512), 0, stream>>>(x0, Amat, sigma, dW, out);
}